// Round 10
// baseline (65.372 us; speedup 1.0000x reference)
//
#include <hip/hip_runtime.h>
#include <stdint.h>

// y[m][n] = scales[n] * sum_k x[m][k]*W[n][k] + bias[n]
// M=128, K=4096, N=11008. x fp32; W int8-valued int32 [N][K]; out fp32.
//
// Round-10 structure (r8's proven LDS gemm + atomic epilogue + finer K-split):
//   init:   out = bias (seed for atomic accumulation; 5.6 MB, ~1us).
//   pack_x: x fp32 -> bf16 in MFMA A-frag order into ws (1 MiB, L2-resident).
//   gemm4w: ks=8 -> 1376 blocks (5.375 work-units/CU >> 3/CU residency ->
//           HW dynamic balancing; r8's 2.69-vs-3 block imbalance ~12% tail
//           becomes ~half-block ~2us). 4 waves, wave = FULL M (128) x 16
//           cols (B crosses L3 exactly once). 3-buffer LDS ring (48 KiB),
//           counted vmcnt(16) 2-deep prefetch -- K-loop IDENTICAL to r8,
//           cpb=8. Epilogue: atomicAdd(out, scales*acc) -- no partials,
//           no reduce kernel (saves 50 MB traffic + a dispatch).
//   NOTE: no spills tolerated (scratch ops would break hand-counted vmcnt).

#define M_ROWS 128
#define K_DIM  4096
#define N_DIM  11008
#define CHUNKS 64                       // K chunks of 64
#define NT64   (N_DIM / 64)             // 172 block n-tiles
#define KSPLIT 8
#define CPB    (CHUNKS / KSPLIT)        // 8 chunks per block
#define XP_BYTES (M_ROWS * K_DIM * 2)   // 1 MiB packed bf16 x

typedef __attribute__((ext_vector_type(8))) short bf16x8;
typedef __attribute__((ext_vector_type(4))) float f32x4;
typedef const unsigned __attribute__((address_space(1)))* gas1_t;
typedef unsigned __attribute__((address_space(3)))* las3_t;

__device__ __forceinline__ unsigned bf16_rn(float f) {
  unsigned u = __float_as_uint(f);
  return (u + 0x7FFFu + ((u >> 16) & 1u)) >> 16;   // round-to-nearest-even
}
// two exact int->f32, pack top halves into 2xbf16 (truncate = exact, |w|<=128)
__device__ __forceinline__ unsigned pk2(int a, int b) {
  unsigned lo = __float_as_uint((float)a), hi = __float_as_uint((float)b);
#if __has_builtin(__builtin_amdgcn_perm)
  return __builtin_amdgcn_perm(hi, lo, 0x07060302u);
#else
  return (hi & 0xFFFF0000u) | (lo >> 16);
#endif
}

__device__ __forceinline__ void gload_lds16(const void* g, void* lds) {
#if __has_builtin(__builtin_amdgcn_global_load_lds)
  // generic LDS pointer low 32 bits == LDS byte offset (validated r2-r8)
  __builtin_amdgcn_global_load_lds((gas1_t)g, (las3_t)(size_t)(unsigned)(size_t)lds,
                                   16, 0, 0);
#else
  *(uint4*)lds = *(const uint4*)g;  // synchronous fallback (correct)
#endif
}

// barrier only: LDS buffer hand-off (no new data consumed)
#define BAR()    asm volatile("s_barrier" ::: "memory")
// wait for all but the newest N vmem ops, then barrier. Per-wave waitcnt
// before s_barrier => at barrier exit, every wave's counted DMAs are done.
#define WBAR16() asm volatile("s_waitcnt vmcnt(16)\n\ts_barrier" ::: "memory")
#define WBAR8()  asm volatile("s_waitcnt vmcnt(8)\n\ts_barrier" ::: "memory")
#define WBAR0()  asm volatile("s_waitcnt vmcnt(0)\n\ts_barrier" ::: "memory")

// ---------------- init: out = bias (atomic-accumulation seed) --------------
__global__ __launch_bounds__(256) void init_out_kernel(
    const float* __restrict__ bias, float* __restrict__ out) {
  const int idx = blockIdx.x * 256 + threadIdx.x;    // float4 units
  const int n4 = N_DIM / 4;                          // 2752
  if (idx >= M_ROWS * n4) return;
  const int c = idx % n4;
  ((float4*)out)[idx] = ((const float4*)bias)[c];
}

// ---------------- pack x: fp32 -> bf16 in A-frag order ----------------
// Chunk kk = 16 KiB: 16B unit u = (mf*2 + s)*64 + lane
// frag (mf,s): lane l holds x[16*mf + (l&15)][kk*64 + s*32 + 8*(l>>4) + j]
__global__ __launch_bounds__(256) void pack_x_kernel(
    const float* __restrict__ x, unsigned short* __restrict__ xp) {
  int tid  = blockIdx.x * 256 + threadIdx.x;   // 65536 threads
  int lane = tid & 63;
  int h    = (tid >> 6) & 1;
  int mf   = (tid >> 7) & 7;
  int kk   = tid >> 10;
  int m     = mf * 16 + (lane & 15);
  int kbase = kk * 64 + h * 32 + ((lane >> 4) * 8);
  const float* src = x + (size_t)m * K_DIM + kbase;
  float4 f0 = *(const float4*)(src);
  float4 f1 = *(const float4*)(src + 4);
  float v[8] = {f0.x, f0.y, f0.z, f0.w, f1.x, f1.y, f1.z, f1.w};
  unsigned po[4];
#pragma unroll
  for (int i = 0; i < 4; ++i)
    po[i] = bf16_rn(v[2 * i]) | (bf16_rn(v[2 * i + 1]) << 16);
  *(uint4*)(xp + (size_t)tid * 8) = *(uint4*)po;
}

// ---------------- 4-wave GEMM: block BM=128 x BN=64, cpb=8 chunks ----------
struct BReg { uint4 v[4]; };   // one chunk of B per lane: 16 ints

__global__ __launch_bounds__(256, 3) void gemm4w_kernel(
    const unsigned short* __restrict__ xp,
    const int* __restrict__ wq,
    const float* __restrict__ scales,
    float* __restrict__ out) {
  __shared__ char As[3 * 16384];       // 3-buffer ring (2 chunks in flight)

  const int tid  = threadIdx.x;
  const int lane = tid & 63;
  const int w    = tid >> 6;           // wave 0..3 -> cols [16w, 16w+16)
  const int nt   = blockIdx.x;         // 0..171
  const int kz   = blockIdx.y;         // 0..7
  const int kk0  = kz * CPB;
  const size_t n0 = (size_t)nt * 64 + (size_t)w * 16;
  const int l15 = lane & 15, lh = lane >> 4;

  // A staging: block covers 16 KiB/chunk; thread stages 4x16B, lane-linear
  const char* agp = (const char*)xp + (size_t)kk0 * 16384 + tid * 16;
  // B: row n0 + l15; ints at (kk0+t)*64 + s*32 + lh*8 .. +8
  const int* bptr = wq + (n0 + (size_t)l15) * K_DIM + (size_t)kk0 * 64 + lh * 8;

  f32x4 acc[8];
  {
    f32x4 z = {0.f, 0.f, 0.f, 0.f};
#pragma unroll
    for (int i = 0; i < 8; ++i) acc[i] = z;
  }

  auto STAGE = [&](int t, int bufOff) {
#pragma unroll
    for (int i = 0; i < 4; ++i)
      gload_lds16(agp + (size_t)t * 16384 + (size_t)i * 4096,
                  As + bufOff + tid * 16 + i * 4096);
  };
  auto LOADB = [&](int t, BReg& R) {
    const int* bp = bptr + t * 64;
    R.v[0] = *(const uint4*)(bp);
    R.v[1] = *(const uint4*)(bp + 4);
    R.v[2] = *(const uint4*)(bp + 32);
    R.v[3] = *(const uint4*)(bp + 36);
  };
  auto COMP = [&](const char* ab, BReg& R) {
    bf16x8 cv[2];
#pragma unroll
    for (int s = 0; s < 2; ++s) {
      union { unsigned u[4]; bf16x8 b; } c;
      c.u[0] = pk2((int)R.v[s * 2].x,     (int)R.v[s * 2].y);
      c.u[1] = pk2((int)R.v[s * 2].z,     (int)R.v[s * 2].w);
      c.u[2] = pk2((int)R.v[s * 2 + 1].x, (int)R.v[s * 2 + 1].y);
      c.u[3] = pk2((int)R.v[s * 2 + 1].z, (int)R.v[s * 2 + 1].w);
      cv[s] = c.b;
    }
#pragma unroll
    for (int mf = 0; mf < 8; ++mf)
#pragma unroll
      for (int s = 0; s < 2; ++s) {
        bf16x8 a = *(const bf16x8*)(ab + (mf * 2 + s) * 1024 + lane * 16);
        acc[mf] = __builtin_amdgcn_mfma_f32_16x16x32_bf16(a, cv[s], acc[mf], 0, 0, 0);
      }
  };

  // phase T: consume chunk T (ring buf T%3, reg R[T%3]); issue chunk T+2 into
  // ring (T+2)%3 (freed at phase T-1). Outstanding before WBAR16: chunks
  // T, T+1, T+2 = 24 ops -> vmcnt(16) drains exactly chunk T's 8.
#define PHASE(T, CBUF, NBUF, RC, RN)              \
    LOADB((T) + 2, RN);                           \
    BAR();                                        \
    STAGE((T) + 2, (NBUF) * 16384);               \
    WBAR16();                                     \
    COMP(As + (CBUF) * 16384, RC);

  BReg R0, R1, R2;
  // prologue: chunks 0,1 in flight (16 ops)
  STAGE(0, 0);
  LOADB(0, R0);
  STAGE(1, 16384);
  LOADB(1, R1);

#pragma unroll 1
  for (int t = 0; t < 6; t += 3) {       // phases 0..5 (issue chunks 2..7)
    PHASE(t + 0, 0, 2, R0, R2);
    PHASE(t + 1, 1, 0, R1, R0);
    PHASE(t + 2, 2, 1, R2, R1);
  }
  WBAR8();                               // chunk 6 resident (buf0, R0)
  COMP(As + 0 * 16384, R0);
  WBAR0();                               // chunk 7 resident (buf1, R1)
  COMP(As + 1 * 16384, R1);
#undef PHASE

  // atomic epilogue: out was seeded with bias; add scales*acc.
  // m = mf*16 + lh*4 + r ; n = n0 + l15
  const size_t n = n0 + (size_t)l15;
  const float sc = scales[n];
  float* ob = out + n;
#pragma unroll
  for (int mf = 0; mf < 8; ++mf) {
    const int mb = mf * 16 + lh * 4;
#pragma unroll
    for (int r = 0; r < 4; ++r)
      atomicAdd(ob + (size_t)(mb + r) * N_DIM, sc * acc[mf][r]);
  }
}

// ---------------- insurance path if ws is tiny ----------------
__global__ __launch_bounds__(256) void naive_kernel(
    const float* __restrict__ x, const int* __restrict__ wq,
    const float* __restrict__ scales, const float* __restrict__ bias,
    float* __restrict__ out) {
  const int n = blockIdx.x * 256 + threadIdx.x;
  const int m = blockIdx.y;
  const float* xr = x + (size_t)m * K_DIM;
  const int* wr = wq + (size_t)n * K_DIM;
  float s = 0.f;
  for (int k = 0; k < K_DIM; k += 4) {
    float4 xv = *(const float4*)(xr + k);
    int4  wv = *(const int4*)(wr + k);
    s += xv.x * (float)wv.x + xv.y * (float)wv.y +
         xv.z * (float)wv.z + xv.w * (float)wv.w;
  }
  out[(size_t)m * N_DIM + n] = scales[n] * s + bias[n];
}

extern "C" void kernel_launch(void* const* d_in, const int* in_sizes, int n_in,
                              void* d_out, int out_size, void* d_ws, size_t ws_size,
                              hipStream_t stream) {
  const float* x      = (const float*)d_in[0];
  const int* wq       = (const int*)d_in[1];
  const float* scales = (const float*)d_in[2];
  const float* bias   = (const float*)d_in[3];
  float* out          = (float*)d_out;

  if (ws_size < (size_t)XP_BYTES) {
    naive_kernel<<<dim3(N_DIM / 256, M_ROWS), 256, 0, stream>>>(x, wq, scales, bias, out);
    return;
  }
  unsigned short* xp = (unsigned short*)d_ws;

  init_out_kernel<<<dim3((M_ROWS * N_DIM / 4 + 255) / 256), 256, 0, stream>>>(bias, out);
  pack_x_kernel<<<256, 256, 0, stream>>>(x, xp);
  gemm4w_kernel<<<dim3(NT64, KSPLIT), 256, 0, stream>>>(xp, wq, scales, out);
}

// Round 11
// 51.538 us; speedup vs baseline: 1.2684x; 1.2684x over previous
//
#include <hip/hip_runtime.h>
#include <stdint.h>

// y[m][n] = scales[n] * sum_k x[m][k]*W[n][k] + bias[n]
// M=128, K=4096, N=11008. x fp32; W int8-valued int32 [N][K]; out fp32.
//
// Round-11 structure (halve per-CU load bytes: A shared across 2x columns):
//   pack_x: x fp32 -> bf16 in MFMA A-frag order into ws (1 MiB, L2-resident).
//   gemm8w: 8 waves (512 thr), wave = FULL M (128) x 16 cols -> BN=128.
//           A-DMA traffic (N/BN)*1MiB drops 176->86 MB (r8 moved A==B==176;
//           measured 16.8 B/cy/CU suggests per-CU load path is the cap).
//           ks=8 -> 688 blocks, cpb=8. 3-buffer LDS ring (48 KiB), counted
//           vmcnt 2-deep: 6 vmem ops/phase (2 A-DMA + 4 B) -> vmcnt(12).
//           2 blocks/CU (launch_bounds(512,4), VGPR cap 128; r8 used 100).
//           Partials: bf16x2 packed along m-pairs -> ks=8 at r8's 22.5 MB.
//   reduce: out = scales*(sum of 8 bf16 partials) + bias (deterministic).
//   NOTE: no spills tolerated (scratch ops would break hand-counted vmcnt).

#define M_ROWS 128
#define K_DIM  4096
#define N_DIM  11008
#define CHUNKS 64                       // K chunks of 64
#define NT128  (N_DIM / 128)            // 86 block n-tiles
#define KSPLIT 8
#define CPB    (CHUNKS / KSPLIT)        // 8 chunks per block
#define XP_BYTES (M_ROWS * K_DIM * 2)   // 1 MiB packed bf16 x
#define PART_U32 ((size_t)64 * N_DIM)   // one kz-slice: uint32 per m-pair

typedef __attribute__((ext_vector_type(8))) short bf16x8;
typedef __attribute__((ext_vector_type(4))) float f32x4;
typedef const unsigned __attribute__((address_space(1)))* gas1_t;
typedef unsigned __attribute__((address_space(3)))* las3_t;

__device__ __forceinline__ unsigned bf16_rn(float f) {
  unsigned u = __float_as_uint(f);
  return (u + 0x7FFFu + ((u >> 16) & 1u)) >> 16;   // round-to-nearest-even
}
// two exact int->f32, pack top halves into 2xbf16 (truncate = exact, |w|<=128)
__device__ __forceinline__ unsigned pk2(int a, int b) {
  unsigned lo = __float_as_uint((float)a), hi = __float_as_uint((float)b);
#if __has_builtin(__builtin_amdgcn_perm)
  return __builtin_amdgcn_perm(hi, lo, 0x07060302u);
#else
  return (hi & 0xFFFF0000u) | (lo >> 16);
#endif
}

__device__ __forceinline__ void gload_lds16(const void* g, void* lds) {
#if __has_builtin(__builtin_amdgcn_global_load_lds)
  // generic LDS pointer low 32 bits == LDS byte offset (validated r2-r10)
  __builtin_amdgcn_global_load_lds((gas1_t)g, (las3_t)(size_t)(unsigned)(size_t)lds,
                                   16, 0, 0);
#else
  *(uint4*)lds = *(const uint4*)g;  // synchronous fallback (correct)
#endif
}

// barrier only: LDS buffer hand-off (no new data consumed)
#define BAR()    asm volatile("s_barrier" ::: "memory")
// wait for all but the newest N vmem ops, then barrier. Per-wave waitcnt
// before s_barrier => at barrier exit, every wave's counted DMAs are done.
#define WBAR12() asm volatile("s_waitcnt vmcnt(12)\n\ts_barrier" ::: "memory")
#define WBAR6()  asm volatile("s_waitcnt vmcnt(6)\n\ts_barrier" ::: "memory")
#define WBAR0()  asm volatile("s_waitcnt vmcnt(0)\n\ts_barrier" ::: "memory")

// ---------------- pack x: fp32 -> bf16 in A-frag order ----------------
// Chunk kk = 16 KiB: 16B unit u = (mf*2 + s)*64 + lane
// frag (mf,s): lane l holds x[16*mf + (l&15)][kk*64 + s*32 + 8*(l>>4) + j]
__global__ __launch_bounds__(256) void pack_x_kernel(
    const float* __restrict__ x, unsigned short* __restrict__ xp) {
  int tid  = blockIdx.x * 256 + threadIdx.x;   // 65536 threads
  int lane = tid & 63;
  int h    = (tid >> 6) & 1;
  int mf   = (tid >> 7) & 7;
  int kk   = tid >> 10;
  int m     = mf * 16 + (lane & 15);
  int kbase = kk * 64 + h * 32 + ((lane >> 4) * 8);
  const float* src = x + (size_t)m * K_DIM + kbase;
  float4 f0 = *(const float4*)(src);
  float4 f1 = *(const float4*)(src + 4);
  float v[8] = {f0.x, f0.y, f0.z, f0.w, f1.x, f1.y, f1.z, f1.w};
  unsigned po[4];
#pragma unroll
  for (int i = 0; i < 4; ++i)
    po[i] = bf16_rn(v[2 * i]) | (bf16_rn(v[2 * i + 1]) << 16);
  *(uint4*)(xp + (size_t)tid * 8) = *(uint4*)po;
}

// ---------------- 8-wave GEMM: block BM=128 x BN=128, cpb=8 chunks ---------
struct BReg { uint4 v[4]; };   // one chunk of B per lane: 16 ints

__global__ __launch_bounds__(512, 4) void gemm8w_kernel(
    const unsigned short* __restrict__ xp,
    const int* __restrict__ wq,
    unsigned* __restrict__ part) {
  __shared__ char As[3 * 16384];       // 3-buffer ring (2 chunks in flight)

  const int tid  = threadIdx.x;        // 0..511
  const int lane = tid & 63;
  const int w    = tid >> 6;           // wave 0..7 -> cols [16w, 16w+16)
  const int nt   = blockIdx.x;         // 0..85
  const int kz   = blockIdx.y;         // 0..7
  const int kk0  = kz * CPB;
  const size_t n0 = (size_t)nt * 128 + (size_t)w * 16;
  const int l15 = lane & 15, lh = lane >> 4;

  // A staging: 16 KiB/chunk; 512 threads x 2 x 16B, lane-linear
  const char* agp = (const char*)xp + (size_t)kk0 * 16384 + tid * 16;
  // B: row n0 + l15; ints at (kk0+t)*64 + s*32 + lh*8 .. +8
  const int* bptr = wq + (n0 + (size_t)l15) * K_DIM + (size_t)kk0 * 64 + lh * 8;

  f32x4 acc[8];
  {
    f32x4 z = {0.f, 0.f, 0.f, 0.f};
#pragma unroll
    for (int i = 0; i < 8; ++i) acc[i] = z;
  }

  auto STAGE = [&](int t, int bufOff) {
    gload_lds16(agp + (size_t)t * 16384,        As + bufOff + tid * 16);
    gload_lds16(agp + (size_t)t * 16384 + 8192, As + bufOff + tid * 16 + 8192);
  };
  auto LOADB = [&](int t, BReg& R) {
    const int* bp = bptr + t * 64;
    R.v[0] = *(const uint4*)(bp);
    R.v[1] = *(const uint4*)(bp + 4);
    R.v[2] = *(const uint4*)(bp + 32);
    R.v[3] = *(const uint4*)(bp + 36);
  };
  auto COMP = [&](const char* ab, BReg& R) {
    bf16x8 cv[2];
#pragma unroll
    for (int s = 0; s < 2; ++s) {
      union { unsigned u[4]; bf16x8 b; } c;
      c.u[0] = pk2((int)R.v[s * 2].x,     (int)R.v[s * 2].y);
      c.u[1] = pk2((int)R.v[s * 2].z,     (int)R.v[s * 2].w);
      c.u[2] = pk2((int)R.v[s * 2 + 1].x, (int)R.v[s * 2 + 1].y);
      c.u[3] = pk2((int)R.v[s * 2 + 1].z, (int)R.v[s * 2 + 1].w);
      cv[s] = c.b;
    }
#pragma unroll
    for (int mf = 0; mf < 8; ++mf)
#pragma unroll
      for (int s = 0; s < 2; ++s) {
        bf16x8 a = *(const bf16x8*)(ab + (mf * 2 + s) * 1024 + lane * 16);
        acc[mf] = __builtin_amdgcn_mfma_f32_16x16x32_bf16(a, cv[s], acc[mf], 0, 0, 0);
      }
  };

  // phase T: consume chunk T (ring buf T%3, reg R[T%3]); issue chunk T+2 into
  // ring (T+2)%3 (freed at phase T-1). 6 vmem ops/phase (2 DMA + 4 B).
  // Outstanding before WBAR12: chunks T,T+1,T+2 = 18 -> drains chunk T's 6.
#define PHASE(T, CBUF, NBUF, RC, RN)              \
    LOADB((T) + 2, RN);                           \
    BAR();                                        \
    STAGE((T) + 2, (NBUF) * 16384);               \
    WBAR12();                                     \
    COMP(As + (CBUF) * 16384, RC);

  BReg R0, R1, R2;
  // prologue: chunks 0,1 in flight (12 ops)
  STAGE(0, 0);
  LOADB(0, R0);
  STAGE(1, 16384);
  LOADB(1, R1);

#pragma unroll 1
  for (int t = 0; t < 6; t += 3) {       // phases 0..5 (issue chunks 2..7)
    PHASE(t + 0, 0, 2, R0, R2);
    PHASE(t + 1, 1, 0, R1, R0);
    PHASE(t + 2, 2, 1, R2, R1);
  }
  WBAR6();                               // chunk 6 resident (buf0, R0)
  COMP(As + 0 * 16384, R0);
  WBAR0();                               // chunk 7 resident (buf1, R1)
  COMP(As + 1 * 16384, R1);
#undef PHASE

  // bf16x2 partial epilogue, packed along m-pairs:
  // rows mb=mf*16+lh*4 .. +3 ; n = n0 + l15 ; element (mp,n) = rows 2mp,2mp+1
  unsigned* pb = part + (size_t)kz * PART_U32 + n0 + l15;
#pragma unroll
  for (int mf = 0; mf < 8; ++mf) {
    const int mb = mf * 16 + lh * 4;     // even
    unsigned u0 = bf16_rn(acc[mf][0]) | (bf16_rn(acc[mf][1]) << 16);
    unsigned u1 = bf16_rn(acc[mf][2]) | (bf16_rn(acc[mf][3]) << 16);
    pb[(size_t)(mb >> 1) * N_DIM]       = u0;
    pb[(size_t)((mb >> 1) + 1) * N_DIM] = u1;
  }
}

// ---------------- combine bf16 partials + epilogue ----------------
__global__ __launch_bounds__(256) void reduce_kernel(
    const unsigned* __restrict__ part, const float* __restrict__ scales,
    const float* __restrict__ bias, float* __restrict__ out) {
  const int mp = blockIdx.y;                        // 0..63 (m-pair)
  const int c4 = blockIdx.x * 256 + threadIdx.x;
  if (c4 >= N_DIM / 4) return;
  const size_t n = (size_t)c4 * 4;
  float s0[4] = {0.f, 0.f, 0.f, 0.f};
  float s1[4] = {0.f, 0.f, 0.f, 0.f};
#pragma unroll
  for (int z = 0; z < KSPLIT; ++z) {
    uint4 q = *(const uint4*)(part + (size_t)z * PART_U32 + (size_t)mp * N_DIM + n);
    const unsigned uu[4] = {q.x, q.y, q.z, q.w};
#pragma unroll
    for (int j = 0; j < 4; ++j) {
      s0[j] += __uint_as_float(uu[j] << 16);
      s1[j] += __uint_as_float(uu[j] & 0xFFFF0000u);
    }
  }
  float4 sc = *(const float4*)(scales + n);
  float4 bi = *(const float4*)(bias + n);
  const float scv[4] = {sc.x, sc.y, sc.z, sc.w};
  const float biv[4] = {bi.x, bi.y, bi.z, bi.w};
  float4 r0, r1;
  float* o0 = out + (size_t)(2 * mp) * N_DIM + n;
  float* o1 = out + (size_t)(2 * mp + 1) * N_DIM + n;
  r0.x = scv[0] * s0[0] + biv[0];  r1.x = scv[0] * s1[0] + biv[0];
  r0.y = scv[1] * s0[1] + biv[1];  r1.y = scv[1] * s1[1] + biv[1];
  r0.z = scv[2] * s0[2] + biv[2];  r1.z = scv[2] * s1[2] + biv[2];
  r0.w = scv[3] * s0[3] + biv[3];  r1.w = scv[3] * s1[3] + biv[3];
  *(float4*)o0 = r0;
  *(float4*)o1 = r1;
}

// ---------------- insurance path if ws is tiny ----------------
__global__ __launch_bounds__(256) void naive_kernel(
    const float* __restrict__ x, const int* __restrict__ wq,
    const float* __restrict__ scales, const float* __restrict__ bias,
    float* __restrict__ out) {
  const int n = blockIdx.x * 256 + threadIdx.x;
  const int m = blockIdx.y;
  const float* xr = x + (size_t)m * K_DIM;
  const int* wr = wq + (size_t)n * K_DIM;
  float s = 0.f;
  for (int k = 0; k < K_DIM; k += 4) {
    float4 xv = *(const float4*)(xr + k);
    int4  wv = *(const int4*)(wr + k);
    s += xv.x * (float)wv.x + xv.y * (float)wv.y +
         xv.z * (float)wv.z + xv.w * (float)wv.w;
  }
  out[(size_t)m * N_DIM + n] = scales[n] * s + bias[n];
}

extern "C" void kernel_launch(void* const* d_in, const int* in_sizes, int n_in,
                              void* d_out, int out_size, void* d_ws, size_t ws_size,
                              hipStream_t stream) {
  const float* x      = (const float*)d_in[0];
  const int* wq       = (const int*)d_in[1];
  const float* scales = (const float*)d_in[2];
  const float* bias   = (const float*)d_in[3];
  float* out          = (float*)d_out;

  const size_t need = (size_t)XP_BYTES + (size_t)KSPLIT * PART_U32 * 4;
  if (ws_size < need) {
    naive_kernel<<<dim3(N_DIM / 256, M_ROWS), 256, 0, stream>>>(x, wq, scales, bias, out);
    return;
  }
  unsigned short* xp = (unsigned short*)d_ws;
  unsigned* part     = (unsigned*)((char*)d_ws + XP_BYTES);

  pack_x_kernel<<<256, 256, 0, stream>>>(x, xp);
  gemm8w_kernel<<<dim3(NT128, KSPLIT), 512, 0, stream>>>(xp, wq, part);
  reduce_kernel<<<dim3((N_DIM / 4 + 255) / 256, 64), 256, 0, stream>>>(
      part, scales, bias, out);
}